// Round 6
// baseline (104.452 us; speedup 1.0000x reference)
//
#include <hip/hip_runtime.h>
#include <hip/hip_bf16.h>

// BlockAttention: paged KV-cache prefill attention, block-causal mask.
// B=4, LQ=512, HQ=16, HKV=8, D=128, CTX=2048, LK=2560.
// R1: XCD-aware block index + register prefetch.
// R2: swizzled K/V LDS, double-buffer, one barrier/tile.
// R3: swapped QK^T -> in-register softmax; zero-shuffle PV (pa in-lane,
//     V^T bit-permuted); cvt_pk; defer-max.
// R4 (reverted): kv-split waves — DS-read halving bought nothing =>
//     kernel is latency-bound, not DS-throughput-bound.
// R5: OCCUPANCY: 256-thread/4-wave blocks over 32 q-rows, grid 512 =>
//     2 independent blocks/CU; one block's compute covers the other's
//     barrier drain. Per-wave work identical to R3. Block stages the
//     full 64-kv tile as two register-set halves issued early.

#define B_    4
#define LQ_   512
#define HQ_   16
#define HKV_  8
#define D_    128
#define BLKSZ_ 256
#define BPS_  8
#define CTX_  2048
#define DIFFB_ 128
#define KT_   64
#define SCALE_ 0.08838834764831845f

typedef __attribute__((ext_vector_type(4))) float f32x4;
typedef __attribute__((ext_vector_type(8))) short bf16x8;

__device__ __forceinline__ unsigned cvt_pk2(float a, float b) {
  union { __hip_bfloat162 h; unsigned u; } x;
  x.h = __float22bfloat162_rn(float2{a, b});
  return x.u;
}
union bf8u { bf16x8 v; unsigned u[4]; };

// ---- K tile swizzle (units: shorts), 16B-chunk XOR ----
__device__ __forceinline__ int kidx(int kv, int d) {
  return kv * 128 + ((((d >> 3) ^ kv) & 15) << 3) + (d & 7);
}
// ---- V^T tile swizzle; p is the PHYSICAL (k-label) kv slot ----
__device__ __forceinline__ int vidx(int d, int p) {
  return d * 64 + ((((p >> 3) ^ d ^ (d >> 3)) & 7) << 3) + (p & 7);
}
// kv bit-permute: swap bits[5:4] <-> bits[3:2] (involution)
__device__ __forceinline__ int pkmap(int kv) {
  return ((kv & 12) << 2) | ((kv & 48) >> 2) | (kv & 3);
}

__global__ __launch_bounds__(256, 2)
void block_attn_kernel(const float* __restrict__ qg,
                       const float* __restrict__ kcur,
                       const float* __restrict__ vcur,
                       const float* __restrict__ kcache,
                       const float* __restrict__ vcache,
                       const int*   __restrict__ btab,
                       float*       __restrict__ out) {
  // grid 512: blk = qb*32 + b*8 + hkv (qb in high bits -> blocks sharing a
  // (b,hkv) K/V panel land on the same XCD under round-robin dispatch).
  const int blk  = blockIdx.x;
  const int hkv  = blk & 7;
  const int b    = (blk >> 3) & 3;
  const int qb   = blk >> 5;                    // 32-row q tile, 0..15
  const int tid  = threadIdx.x;
  const int lane = tid & 63;
  const int wave = tid >> 6;                    // 0..3
  const int lo   = lane & 15;
  const int hi   = lane >> 4;
  const int hq   = hkv * 2 + (wave >> 1);       // 2 heads per block
  const int qrow0 = qb * 32 + (wave & 1) * 16;  // wave's 16 q rows
  const int limit  = CTX_ + (qb / 4 + 1) * DIFFB_;
  const int ntiles = limit / KT_;

  __shared__ __align__(16) short Kl[2][KT_ * D_];   // 2 x 16 KiB, swizzled
  __shared__ __align__(16) short Vl[2][D_ * KT_];   // 2 x 16 KiB, V^T perm+swz

  // ---- Q fragments (scaled bf16). frag: col=lo, k=hi*8+j ----
  bf16x8 qf[4];
  {
    const float* qr = qg + ((size_t)((b * LQ_ + qrow0 + lo)) * HQ_ + hq) * D_;
#pragma unroll
    for (int db = 0; db < 4; ++db) {
      const int d0 = db * 32 + hi * 8;
      f32x4 a = *(const f32x4*)(qr + d0);
      f32x4 c4 = *(const f32x4*)(qr + d0 + 4);
      bf8u f;
      f.u[0] = cvt_pk2(a[0] * SCALE_, a[1] * SCALE_);
      f.u[1] = cvt_pk2(a[2] * SCALE_, a[3] * SCALE_);
      f.u[2] = cvt_pk2(c4[0] * SCALE_, c4[1] * SCALE_);
      f.u[3] = cvt_pk2(c4[2] * SCALE_, c4[3] * SCALE_);
      qf[db] = f.v;
    }
  }

  f32x4 oacc[8];
#pragma unroll
  for (int i = 0; i < 8; ++i) oacc[i] = (f32x4){0.f, 0.f, 0.f, 0.f};
  float mrow = -1e30f, lrow = 0.f;     // per-lane: ONE q-row (q = lo)

  // ---- staging: 256 threads stage the 64-kv tile in two halves h=0,1 ----
  f32x4 kreg[2][4], vreg[2][4];

  auto issue_loads = [&](int t, int h) {
    const int c  = h * 32 + (tid >> 3);   // kv row 0..63
    const int e  = tid & 7;
    const int r0 = c & ~1;
    const int ep = ((c & 1) << 3) | e;
    const int kbase = t * KT_;            // tile never straddles CTX
    const float *kr, *vr0;
    if (kbase < CTX_) {
      const int pb = btab[b * BPS_ + (kbase >> 8)];
      const int ro = (kbase & 255);
      kr  = kcache + ((size_t)(pb * BLKSZ_ + ro + c)  * HKV_ + hkv) * D_;
      vr0 = vcache + ((size_t)(pb * BLKSZ_ + ro + r0) * HKV_ + hkv) * D_;
    } else {
      const int cur = kbase - CTX_;
      kr  = kcur + ((size_t)(b * LQ_ + cur + c)  * HKV_ + hkv) * D_;
      vr0 = vcur + ((size_t)(b * LQ_ + cur + r0) * HKV_ + hkv) * D_;
    }
#pragma unroll
    for (int i2 = 0; i2 < 4; ++i2)
      kreg[h][i2] = *(const f32x4*)(kr + (e + i2 * 8) * 4);
    const int vd0 = ep * 8;
    vreg[h][0] = *(const f32x4*)(vr0 + vd0);
    vreg[h][1] = *(const f32x4*)(vr0 + vd0 + 4);
    vreg[h][2] = *(const f32x4*)(vr0 + HKV_ * D_ + vd0);
    vreg[h][3] = *(const f32x4*)(vr0 + HKV_ * D_ + vd0 + 4);
  };

  auto write_lds = [&](int bsel, int h) {
    const int c  = h * 32 + (tid >> 3);
    const int e  = tid & 7;
    const int r0 = c & ~1;
    const int ep = ((c & 1) << 3) | e;
    const int pr = pkmap(r0);
    short* Kb = Kl[bsel];
    short* Vb = Vl[bsel];
#pragma unroll
    for (int i2 = 0; i2 < 4; ++i2) {
      const int d0 = (e + i2 * 8) * 4;
      f32x4 kv = kreg[h][i2];
      *(unsigned*)&Kb[kidx(c, d0)]     = cvt_pk2(kv[0], kv[1]);
      *(unsigned*)&Kb[kidx(c, d0 + 2)] = cvt_pk2(kv[2], kv[3]);
    }
    const int vd0 = ep * 8;
#pragma unroll
    for (int j = 0; j < 4; ++j) {
      *(unsigned*)&Vb[vidx(vd0 + j,     pr)] = cvt_pk2(vreg[h][0][j], vreg[h][2][j]);
      *(unsigned*)&Vb[vidx(vd0 + 4 + j, pr)] = cvt_pk2(vreg[h][1][j], vreg[h][3][j]);
    }
  };

  issue_loads(0, 0);
  issue_loads(0, 1);
  write_lds(0, 0);
  write_lds(0, 1);
  __syncthreads();

  for (int t = 0; t < ntiles; ++t) {
    const int bsel = t & 1;
    const short* Kb = Kl[bsel];
    const short* Vb = Vl[bsel];
    const bool pf = (t + 1 < ntiles);
    if (pf) { issue_loads(t + 1, 0); issue_loads(t + 1, 1); }

    // ---- S^T = K Q^T : sacc[cs][i] = S[q=lo][kv=cs*16+hi*4+i] ----
    f32x4 sacc[4];
#pragma unroll
    for (int cs = 0; cs < 4; ++cs) sacc[cs] = (f32x4){0.f, 0.f, 0.f, 0.f};
#pragma unroll
    for (int cs = 0; cs < 4; ++cs) {
#pragma unroll
      for (int db = 0; db < 4; ++db) {
        bf16x8 kf = *(const bf16x8*)&Kb[kidx(cs * 16 + lo, db * 32 + hi * 8)];
        sacc[cs] = __builtin_amdgcn_mfma_f32_16x16x32_bf16(kf, qf[db], sacc[cs], 0, 0, 0);
      }
    }

    // ---- in-register online softmax (one q-row per lane) ----
    float mx;
    {
      float m0 = fmaxf(fmaxf(sacc[0][0], sacc[0][1]), fmaxf(sacc[0][2], sacc[0][3]));
      float m1 = fmaxf(fmaxf(sacc[1][0], sacc[1][1]), fmaxf(sacc[1][2], sacc[1][3]));
      float m2 = fmaxf(fmaxf(sacc[2][0], sacc[2][1]), fmaxf(sacc[2][2], sacc[2][3]));
      float m3 = fmaxf(fmaxf(sacc[3][0], sacc[3][1]), fmaxf(sacc[3][2], sacc[3][3]));
      mx = fmaxf(fmaxf(m0, m1), fmaxf(m2, m3));
      mx = fmaxf(mx, __shfl_xor(mx, 16));
      mx = fmaxf(mx, __shfl_xor(mx, 32));
    }
    const bool keep = __all(mx - mrow <= 8.0f);   // defer-max (T13)
    const float mnew = keep ? mrow : fmaxf(mrow, mx);
    float rs = 0.f;
#pragma unroll
    for (int cs = 0; cs < 4; ++cs)
#pragma unroll
      for (int i = 0; i < 4; ++i) {
        const float p = __expf(sacc[cs][i] - mnew);
        sacc[cs][i] = p;
        rs += p;
      }
    rs += __shfl_xor(rs, 16);
    rs += __shfl_xor(rs, 32);
    if (keep) {
      lrow += rs;
    } else {
      const float sc = __expf(mrow - mnew);
      lrow = lrow * sc + rs;
      mrow = mnew;
#pragma unroll
      for (int dt = 0; dt < 8; ++dt) oacc[dt] *= sc;
    }

    // ---- pack P in-lane (zero shuffles) ----
    bf16x8 pa[2];
#pragma unroll
    for (int ch = 0; ch < 2; ++ch) {
      bf8u p;
      p.u[0] = cvt_pk2(sacc[2 * ch][0],     sacc[2 * ch][1]);
      p.u[1] = cvt_pk2(sacc[2 * ch][2],     sacc[2 * ch][3]);
      p.u[2] = cvt_pk2(sacc[2 * ch + 1][0], sacc[2 * ch + 1][1]);
      p.u[3] = cvt_pk2(sacc[2 * ch + 1][2], sacc[2 * ch + 1][3]);
      pa[ch] = p.v;
    }

    if (pf) write_lds(bsel ^ 1, 0);   // h0 landed under QK+softmax

    // ---- O^T += V^T P^T ----
#pragma unroll
    for (int ch = 0; ch < 2; ++ch) {
#pragma unroll
      for (int dt = 0; dt < 8; ++dt) {
        bf16x8 vf = *(const bf16x8*)&Vb[vidx(dt * 16 + lo, hi * 16 + ch * 8)];
        oacc[dt] = __builtin_amdgcn_mfma_f32_16x16x32_bf16(vf, pa[ch], oacc[dt], 0, 0, 0);
      }
    }

    if (pf) write_lds(bsel ^ 1, 1);   // h1 landed under PV
    __syncthreads();
  }

  // ---- epilogue: lane owns O[q=lo][dout = dt*16 + hi*4 + i] ----
  const float inv = 1.f / lrow;
  float* orow = out + ((size_t)(b * LQ_ + qrow0 + lo) * HQ_ + hq) * D_;
#pragma unroll
  for (int dt = 0; dt < 8; ++dt) {
    f32x4 o4 = oacc[dt] * inv;
    *(f32x4*)(orow + dt * 16 + hi * 4) = o4;
  }
}

extern "C" void kernel_launch(void* const* d_in, const int* in_sizes, int n_in,
                              void* d_out, int out_size, void* d_ws, size_t ws_size,
                              hipStream_t stream) {
  (void)in_sizes; (void)n_in; (void)out_size; (void)d_ws; (void)ws_size;
  const float* q      = (const float*)d_in[0];
  const float* k      = (const float*)d_in[1];
  const float* v      = (const float*)d_in[2];
  const float* kcache = (const float*)d_in[3];
  const float* vcache = (const float*)d_in[4];
  const int*   btab   = (const int*)d_in[5];
  float* out = (float*)d_out;

  block_attn_kernel<<<dim3(B_ * HKV_ * (LQ_ / 32)), dim3(256), 0, stream>>>(
      q, k, v, kcache, vcache, btab, out);
}

// Round 7
// 87.127 us; speedup vs baseline: 1.1988x; 1.1988x over previous
//
#include <hip/hip_runtime.h>
#include <hip/hip_bf16.h>

// BlockAttention: paged KV-cache prefill attention, block-causal mask.
// B=4, LQ=512, HQ=16, HKV=8, D=128, CTX=2048, LK=2560.
// R1: XCD-aware block index + register prefetch.
// R2: swizzled K/V LDS, double-buffer, one barrier/tile.
// R3: swapped QK^T -> in-register softmax; zero-shuffle PV; defer-max.
// R4 (neutral): kv-split waves at 8 waves/CU — proved DS not the limit.
// R5 (FAILED): 2x 256-thr blocks = same 8 waves/CU, double staging.
// R6: 1024-thread block (16 waves = 4/SIMD), grid 256 = 1 block/CU.
//     8 (q,head) groups x 2 kv-halves (R4 algebra). Staging bytes per CU
//     unchanged vs R3. kv-half pairs merged once at end via LDS overlay.

#define B_    4
#define LQ_   512
#define HQ_   16
#define HKV_  8
#define D_    128
#define BLKSZ_ 256
#define BPS_  8
#define CTX_  2048
#define DIFFB_ 128
#define KT_   64
#define SCALE_ 0.08838834764831845f

typedef __attribute__((ext_vector_type(4))) float f32x4;
typedef __attribute__((ext_vector_type(8))) short bf16x8;

__device__ __forceinline__ unsigned cvt_pk2(float a, float b) {
  union { __hip_bfloat162 h; unsigned u; } x;
  x.h = __float22bfloat162_rn(float2{a, b});
  return x.u;
}
union bf8u { bf16x8 v; unsigned u[4]; };

// ---- K tile swizzle (units: shorts), 16B-chunk XOR ----
__device__ __forceinline__ int kidx(int kv, int d) {
  return kv * 128 + ((((d >> 3) ^ kv) & 15) << 3) + (d & 7);
}
// ---- V^T tile swizzle; p is the PHYSICAL (k-label) kv slot ----
__device__ __forceinline__ int vidx(int d, int p) {
  return d * 64 + ((((p >> 3) ^ d ^ (d >> 3)) & 7) << 3) + (p & 7);
}
// kv -> phys k-label within a 32-half: [4][3:2][1:0] -> [3:2][4][1:0]
__device__ __forceinline__ int pk32(int w) {
  return (((w >> 2) & 3) << 3) | (((w >> 4) & 1) << 2) | (w & 3);
}

__global__ __launch_bounds__(1024)
void block_attn_kernel(const float* __restrict__ qg,
                       const float* __restrict__ kcur,
                       const float* __restrict__ vcur,
                       const float* __restrict__ kcache,
                       const float* __restrict__ vcache,
                       const int*   __restrict__ btab,
                       float*       __restrict__ out) {
  // grid 256: blk = qb*32 + b*8 + hkv (qb high bits -> same (b,hkv) per XCD)
  const int blk  = blockIdx.x;
  const int hkv  = blk & 7;
  const int b    = (blk >> 3) & 3;
  const int qb   = blk >> 5;                    // 64-row q tile, 0..7
  const int tid  = threadIdx.x;
  const int lane = tid & 63;
  const int wave = tid >> 6;                    // 0..15
  const int lo   = lane & 15;
  const int hi   = lane >> 4;
  const int g2   = wave >> 1;                   // (q,head) group 0..7
  const int kvh  = wave & 1;                    // kv half 0..1
  const int hq   = hkv * 2 + (g2 >> 2);
  const int qrow0 = qb * 64 + (g2 & 3) * 16;    // wave's 16 q rows
  const int limit  = CTX_ + (qb / 2 + 1) * DIFFB_;
  const int ntiles = limit / KT_;

  // K buffers @0,16384; V buffers @32768,49152 (bytes). Merge scratch
  // Os (128 row-heads x 128 f32 = 64KB) overlays everything after loop.
  __shared__ __align__(16) char smem_raw[65536];
  __shared__ float ms[8][16], ls[8][16];
  float* Os = (float*)smem_raw;

  // ---- Q fragment (scaled bf16): B-frag col=lo(q), k=hi*8+j ----
  bf16x8 qf[4];
  {
    const float* qr = qg + ((size_t)((b * LQ_ + qrow0 + lo)) * HQ_ + hq) * D_;
#pragma unroll
    for (int db = 0; db < 4; ++db) {
      const int d0 = db * 32 + hi * 8;
      f32x4 a = *(const f32x4*)(qr + d0);
      f32x4 c4 = *(const f32x4*)(qr + d0 + 4);
      bf8u f;
      f.u[0] = cvt_pk2(a[0] * SCALE_, a[1] * SCALE_);
      f.u[1] = cvt_pk2(a[2] * SCALE_, a[3] * SCALE_);
      f.u[2] = cvt_pk2(c4[0] * SCALE_, c4[1] * SCALE_);
      f.u[3] = cvt_pk2(c4[2] * SCALE_, c4[3] * SCALE_);
      qf[db] = f.v;
    }
  }

  f32x4 oacc[8];
#pragma unroll
  for (int i = 0; i < 8; ++i) oacc[i] = (f32x4){0.f, 0.f, 0.f, 0.f};
  float mrow = -1e30f, lrow = 0.f;   // per-lane: ONE q-row, 32-kv half

  // ---- staging: 1024 threads stage the 64-kv tile (4 f32x4 each) ----
  const int c  = tid >> 4;              // kv row 0..63
  const int e  = tid & 15;
  const int r0 = c & ~1;                // V row-pair base
  const int ep = (c & 1) * 16 + e;      // V d-chunk selector 0..31
  const int pr = (r0 & 32) + pk32(r0 & 31);   // V phys slot (even)
  f32x4 kreg[2], vreg[2];

  auto issue_loads = [&](int t) {
    const int kbase = t * KT_;          // tile never straddles CTX
    const float *kr, *vr0;
    if (kbase < CTX_) {
      const int pb = btab[b * BPS_ + (kbase >> 8)];
      const int ro = (kbase & 255);
      kr  = kcache + ((size_t)(pb * BLKSZ_ + ro + c)  * HKV_ + hkv) * D_;
      vr0 = vcache + ((size_t)(pb * BLKSZ_ + ro + r0) * HKV_ + hkv) * D_;
    } else {
      const int cur = kbase - CTX_;
      kr  = kcur + ((size_t)(b * LQ_ + cur + c)  * HKV_ + hkv) * D_;
      vr0 = vcur + ((size_t)(b * LQ_ + cur + r0) * HKV_ + hkv) * D_;
    }
    const int kd0 = e * 8;
    kreg[0] = *(const f32x4*)(kr + kd0);
    kreg[1] = *(const f32x4*)(kr + kd0 + 4);
    const int vd0 = ep * 4;
    vreg[0] = *(const f32x4*)(vr0 + vd0);
    vreg[1] = *(const f32x4*)(vr0 + HKV_ * D_ + vd0);
  };

  auto write_lds = [&](int bsel) {
    short* Kb = (short*)(smem_raw + bsel * 16384);
    short* Vb = (short*)(smem_raw + 32768 + bsel * 16384);
    const int kd0 = e * 8;
    *(unsigned*)&Kb[kidx(c, kd0)]     = cvt_pk2(kreg[0][0], kreg[0][1]);
    *(unsigned*)&Kb[kidx(c, kd0 + 2)] = cvt_pk2(kreg[0][2], kreg[0][3]);
    *(unsigned*)&Kb[kidx(c, kd0 + 4)] = cvt_pk2(kreg[1][0], kreg[1][1]);
    *(unsigned*)&Kb[kidx(c, kd0 + 6)] = cvt_pk2(kreg[1][2], kreg[1][3]);
    const int vd0 = ep * 4;
#pragma unroll
    for (int j = 0; j < 4; ++j)
      *(unsigned*)&Vb[vidx(vd0 + j, pr)] = cvt_pk2(vreg[0][j], vreg[1][j]);
  };

  issue_loads(0);
  write_lds(0);
  __syncthreads();

  for (int t = 0; t < ntiles; ++t) {
    const int bsel = t & 1;
    const short* Kb = (const short*)(smem_raw + bsel * 16384);
    const short* Vb = (const short*)(smem_raw + 32768 + bsel * 16384);
    if (t + 1 < ntiles) issue_loads(t + 1);

    // ---- S^T = K Q^T on this wave's 32-kv half: 8 reads, 8 MFMAs ----
    f32x4 sacc[2];
    sacc[0] = (f32x4){0.f, 0.f, 0.f, 0.f};
    sacc[1] = (f32x4){0.f, 0.f, 0.f, 0.f};
#pragma unroll
    for (int cs = 0; cs < 2; ++cs)
#pragma unroll
      for (int db = 0; db < 4; ++db) {
        bf16x8 kf = *(const bf16x8*)&Kb[kidx(kvh * 32 + cs * 16 + lo,
                                             db * 32 + hi * 8)];
        sacc[cs] = __builtin_amdgcn_mfma_f32_16x16x32_bf16(kf, qf[db], sacc[cs], 0, 0, 0);
      }

    // ---- in-register online softmax (one q-row per lane, 32 kv) ----
    float mx;
    {
      float m0 = fmaxf(fmaxf(sacc[0][0], sacc[0][1]), fmaxf(sacc[0][2], sacc[0][3]));
      float m1 = fmaxf(fmaxf(sacc[1][0], sacc[1][1]), fmaxf(sacc[1][2], sacc[1][3]));
      mx = fmaxf(m0, m1);
      mx = fmaxf(mx, __shfl_xor(mx, 16));
      mx = fmaxf(mx, __shfl_xor(mx, 32));
    }
    const bool keep = __all(mx - mrow <= 8.0f);   // defer-max (T13)
    const float mnew = keep ? mrow : fmaxf(mrow, mx);
    float rs = 0.f;
#pragma unroll
    for (int cs = 0; cs < 2; ++cs)
#pragma unroll
      for (int i = 0; i < 4; ++i) {
        const float p = __expf(sacc[cs][i] - mnew);
        sacc[cs][i] = p;
        rs += p;
      }
    rs += __shfl_xor(rs, 16);
    rs += __shfl_xor(rs, 32);
    if (keep) {
      lrow += rs;
    } else {
      const float sc = __expf(mrow - mnew);
      lrow = lrow * sc + rs;
      mrow = mnew;
#pragma unroll
      for (int dt = 0; dt < 8; ++dt) oacc[dt] *= sc;
    }

    // ---- pack P in-lane: k-label = pk32(kv_local) ----
    bf16x8 pa;
    {
      bf8u p;
      p.u[0] = cvt_pk2(sacc[0][0], sacc[0][1]);
      p.u[1] = cvt_pk2(sacc[0][2], sacc[0][3]);
      p.u[2] = cvt_pk2(sacc[1][0], sacc[1][1]);
      p.u[3] = cvt_pk2(sacc[1][2], sacc[1][3]);
      pa = p.v;
    }

    // ---- O^T += V^T P^T : 8 reads, 8 MFMAs ----
#pragma unroll
    for (int dt = 0; dt < 8; ++dt) {
      bf16x8 vf = *(const bf16x8*)&Vb[vidx(dt * 16 + lo, kvh * 32 + hi * 8)];
      oacc[dt] = __builtin_amdgcn_mfma_f32_16x16x32_bf16(vf, pa, oacc[dt], 0, 0, 0);
    }

    if (t + 1 < ntiles) write_lds(bsel ^ 1);
    __syncthreads();
  }

  // ---- merge kv-halves: kvh=1 publishes, kvh=0 combines + stores ----
  if (kvh == 1) {
#pragma unroll
    for (int dt = 0; dt < 8; ++dt)
      *(f32x4*)&Os[(size_t)(g2 * 16 + lo) * 128 + dt * 16 + hi * 4] = oacc[dt];
    if (hi == 0) { ms[g2][lo] = mrow; ls[g2][lo] = lrow; }
  }
  __syncthreads();
  if (kvh == 0) {
    const float m1 = ms[g2][lo], l1 = ls[g2][lo];
    const float mstar = fmaxf(mrow, m1);
    const float a0 = __expf(mrow - mstar);
    const float a1 = __expf(m1 - mstar);
    const float linv = 1.f / (lrow * a0 + l1 * a1);
    float* orow = out + ((size_t)(b * LQ_ + qrow0 + lo) * HQ_ + hq) * D_;
#pragma unroll
    for (int dt = 0; dt < 8; ++dt) {
      f32x4 o1 = *(const f32x4*)&Os[(size_t)(g2 * 16 + lo) * 128 + dt * 16 + hi * 4];
      f32x4 o = (oacc[dt] * a0 + o1 * a1) * linv;
      *(f32x4*)(orow + dt * 16 + hi * 4) = o;
    }
  }
}

extern "C" void kernel_launch(void* const* d_in, const int* in_sizes, int n_in,
                              void* d_out, int out_size, void* d_ws, size_t ws_size,
                              hipStream_t stream) {
  (void)in_sizes; (void)n_in; (void)out_size; (void)d_ws; (void)ws_size;
  const float* q      = (const float*)d_in[0];
  const float* k      = (const float*)d_in[1];
  const float* v      = (const float*)d_in[2];
  const float* kcache = (const float*)d_in[3];
  const float* vcache = (const float*)d_in[4];
  const int*   btab   = (const int*)d_in[5];
  float* out = (float*)d_out;

  block_attn_kernel<<<dim3(B_ * HKV_ * (LQ_ / 64)), dim3(1024), 0, stream>>>(
      q, k, v, kcache, vcache, btab, out);
}